// Round 10
// baseline (236.601 us; speedup 1.0000x reference)
//
#include <hip/hip_runtime.h>
#include <hip/hip_bf16.h>

// LocalSelfAttention: B=4, S=4096, E=1024, WINDOW=256, SCALE=0.125
// Algebra: scores_ij = (x G + u)_i . x_j (row-consts cancel in softmax),
//   G = Wq^T Wk, u = Wk^T bq.  Since attn rows sum to 1:
//   out = attn @ (x W2^T) + b2 + x,  W2 = Wo Wv, b2 = Wo bv + bo.
// Round 10: gemm_yv -> global_load_lds staging (m97 structure);
//   attn -> barrier-free QK^T/PV with direct-global MFMA fragments
//   (LDS only for P + rmax/rsum = 17.4 KB), fp32 epilogue kept.

typedef unsigned short u16;
typedef __attribute__((ext_vector_type(8))) short short8;   // 8 bf16
typedef __attribute__((ext_vector_type(4))) short short4v;  // 4 bf16 (8B)
typedef __attribute__((ext_vector_type(4))) float f32x4;

__device__ __forceinline__ u16 f2bf(float f) {
    __hip_bfloat16 h = __float2bfloat16(f);
    return __builtin_bit_cast(u16, h);
}

__device__ __forceinline__ void gl_lds16(const u16* g, u16* l) {
    __builtin_amdgcn_global_load_lds(
        (const __attribute__((address_space(1))) void*)g,
        (__attribute__((address_space(3))) void*)l,
        16, 0, 0);
}

// ---------------- cast fp32 -> bf16, vectorized ----------------
__global__ void cast_f32_bf16(const float* __restrict__ src, u16* __restrict__ dst, int n) {
    int i = (blockIdx.x * 256 + threadIdx.x) * 8;
    if (i >= n) return;
    const float4* s = (const float4*)(src + i);
    float4 a = s[0], b = s[1];
    short8 o;
    o[0] = (short)f2bf(a.x); o[1] = (short)f2bf(a.y); o[2] = (short)f2bf(a.z); o[3] = (short)f2bf(a.w);
    o[4] = (short)f2bf(b.x); o[5] = (short)f2bf(b.y); o[6] = (short)f2bf(b.z); o[7] = (short)f2bf(b.w);
    *(short8*)(dst + i) = o;
}

// ---------------- weight casts: WqT, WkT, WvT (transposed), Wob (straight) ----------------
__global__ void wcast(const float* __restrict__ Wq, const float* __restrict__ Wk,
                      const float* __restrict__ Wv, const float* __restrict__ Wo,
                      u16* __restrict__ WqT, u16* __restrict__ WkT,
                      u16* __restrict__ WvT, u16* __restrict__ Wob)
{
    __shared__ float lt[64][65];
    const int which = blockIdx.x >> 8;
    const int bid = blockIdx.x & 255;
    const int c0 = (bid & 15) * 64, r0 = (bid >> 4) * 64;
    const int t = threadIdx.x;
    const int tr = t >> 3, tc = (t & 7) * 8;
    const float* src = which == 0 ? Wq : which == 1 ? Wk : which == 2 ? Wv : Wo;
    if (which == 3) {
#pragma unroll
        for (int p = 0; p < 2; ++p) {
            int r = p * 32 + tr;
            const float* s = src + (size_t)(r0 + r) * 1024 + c0 + tc;
            float4 a = *(const float4*)s, b = *(const float4*)(s + 4);
            short8 o;
            o[0] = (short)f2bf(a.x); o[1] = (short)f2bf(a.y); o[2] = (short)f2bf(a.z); o[3] = (short)f2bf(a.w);
            o[4] = (short)f2bf(b.x); o[5] = (short)f2bf(b.y); o[6] = (short)f2bf(b.z); o[7] = (short)f2bf(b.w);
            *(short8*)(Wob + (size_t)(r0 + r) * 1024 + c0 + tc) = o;
        }
        return;
    }
    u16* dst = which == 0 ? WqT : which == 1 ? WkT : WvT;
#pragma unroll
    for (int p = 0; p < 2; ++p) {
        int r = p * 32 + tr;
        const float* s = src + (size_t)(r0 + r) * 1024 + c0 + tc;
        float4 a = *(const float4*)s, b = *(const float4*)(s + 4);
        lt[r][tc + 0] = a.x; lt[r][tc + 1] = a.y; lt[r][tc + 2] = a.z; lt[r][tc + 3] = a.w;
        lt[r][tc + 4] = b.x; lt[r][tc + 5] = b.y; lt[r][tc + 6] = b.z; lt[r][tc + 7] = b.w;
    }
    __syncthreads();
#pragma unroll
    for (int p = 0; p < 2; ++p) {
        int r = p * 32 + tr;
        short8 o;
#pragma unroll
        for (int j = 0; j < 8; ++j) o[j] = (short)f2bf(lt[tc + j][r]);
        *(short8*)(dst + (size_t)(c0 + r) * 1024 + r0 + tc) = o;
    }
}

// ---------------- u = Wk^T bq ; b2 = Wo bv + bo (fp32) ----------------
__global__ void ub2(const float* __restrict__ Wk, const float* __restrict__ bq,
                    const float* __restrict__ Wo, const float* __restrict__ bv,
                    const float* __restrict__ bo, float* __restrict__ u, float* __restrict__ b2)
{
    const int t = threadIdx.x, bid = blockIdx.x;
    if (bid < 4) {
        int b = bid * 256 + t;
        float acc = 0.f;
        for (int o = 0; o < 1024; ++o) acc += Wk[(size_t)o * 1024 + b] * bq[o];
        u[b] = acc;
    } else {
        int n = (bid - 4) * 16 + (t >> 4);
        int l = t & 15;
        float acc = 0.f;
        for (int m = l; m < 1024; m += 16) acc += Wo[(size_t)n * 1024 + m] * bv[m];
#pragma unroll
        for (int s = 1; s < 16; s <<= 1) acc += __shfl_xor(acc, s, 64);
        if (l == 0) b2[n] = acc + bo[n];
    }
}

// ---------------- dual small GEMM (1024^3): H = WkT @ WqT^T, W2 = Wob @ WvT^T ----------------
__global__ __launch_bounds__(256, 4) void gemm_small_dual(
    const u16* __restrict__ HA, const u16* __restrict__ HB, u16* __restrict__ HC,
    const u16* __restrict__ WA, const u16* __restrict__ WB, u16* __restrict__ WC)
{
    __shared__ __align__(16) u16 At[64 * 64], Bt[64 * 64];
    const bool sec = blockIdx.x >= 256;
    const u16* A = sec ? WA : HA;
    const u16* B = sec ? WB : HB;
    u16* C = sec ? WC : HC;
    const int bid = blockIdx.x & 255;
    const int m0 = (bid >> 4) * 64, n0 = (bid & 15) * 64;
    const int t = threadIdx.x, lane = t & 63, w = t >> 6;
    const int l15 = lane & 15, lk = lane >> 4;

    f32x4 acc[4];
#pragma unroll
    for (int m = 0; m < 4; ++m) acc[m] = (f32x4){0.f, 0.f, 0.f, 0.f};

    for (int k0 = 0; k0 < 1024; k0 += 64) {
        __syncthreads();
#pragma unroll
        for (int p = 0; p < 2; ++p) {
            int e = p * 2048 + t * 8;
            int row = e >> 6, col = e & 63;
            short8 va = *(const short8*)(A + (size_t)(m0 + row) * 1024 + k0 + col);
            *(short8*)((char*)At + row * 128 + ((col * 2) ^ ((row & 7) << 4))) = va;
            short8 vb = *(const short8*)(B + (size_t)(n0 + row) * 1024 + k0 + col);
            *(short8*)((char*)Bt + row * 128 + ((col * 2) ^ ((row & 7) << 4))) = vb;
        }
        __syncthreads();
#pragma unroll
        for (int ks = 0; ks < 2; ++ks) {
            int bc = ks * 64 + lk * 16;
            int brow = w * 16 + l15;
            short8 bfr = *(const short8*)((char*)Bt + brow * 128 + (bc ^ ((brow & 7) << 4)));
#pragma unroll
            for (int m = 0; m < 4; ++m) {
                int arow = m * 16 + l15;
                short8 af = *(const short8*)((char*)At + arow * 128 + (bc ^ ((arow & 7) << 4)));
                acc[m] = __builtin_amdgcn_mfma_f32_16x16x32_bf16(af, bfr, acc[m], 0, 0, 0);
            }
        }
    }
#pragma unroll
    for (int m = 0; m < 4; ++m)
#pragma unroll
        for (int r = 0; r < 4; ++r) {
            int row = m0 + m * 16 + lk * 4 + r;
            int col = n0 + w * 16 + l15;
            C[(size_t)row * 1024 + col] = f2bf(acc[m][r]);
        }
}

// ---------------- fused dual GEMM: y = x@H + u ; v2t = (x@W2^T)^T ----------------
// 128^2 tile, 256 thr / 4 waves, global_load_lds staging (m97 structure).
// Grid dim3(16,128); tn<8 -> y from Hb; tn>=8 -> v2 transposed from W2b.
__global__ __launch_bounds__(256, 2) void gemm_yv(
    const u16* __restrict__ A, const u16* __restrict__ BH, const u16* __restrict__ BW,
    const float* __restrict__ ub, u16* __restrict__ Y, u16* __restrict__ V2t)
{
    __shared__ __align__(16) u16 At[8192];
    __shared__ __align__(16) u16 Bt[8192];
    const int t = threadIdx.x;
    const int lane = t & 63;
    const int w = t >> 6;
    const int wm = w >> 1, wn = w & 1;
    const int l15 = lane & 15, lk = lane >> 4;
    const int K = 1024;

    const int bid = blockIdx.y * gridDim.x + blockIdx.x;   // gridDim.x == 16
    const int cpx = 2048 >> 3;
    const int swz = (bid & 7) * cpx + (bid >> 3);
    const int tn = swz & 15;
    const int tm = swz >> 4;
    const int m0 = tm * 128;
    const bool isv = tn >= 8;
    const int n0 = (tn & 7) * 128;
    const u16* B = isv ? BW : BH;

    // gl_lds staging geometry: linear dest byte = c*4096 + w*1024 + lane*16
    //   -> row = c*32 + w*8 + (lane>>3), phys slot = lane&7;
    //   source col-group s = (lane&7) ^ (row&7) = (lane&7) ^ (lane>>3).
    const int sr = lane >> 3;
    const int ss = (lane & 7) ^ sr;

    f32x4 acc[4][4];
#pragma unroll
    for (int m = 0; m < 4; ++m)
#pragma unroll
        for (int n = 0; n < 4; ++n)
            acc[m][n] = (f32x4){0.f, 0.f, 0.f, 0.f};

    for (int k0 = 0; k0 < K; k0 += 64) {
        __syncthreads();                         // prev compute done; LDS free
#pragma unroll
        for (int c = 0; c < 4; ++c) {
            int row = c * 32 + w * 8 + sr;
            gl_lds16(A + (size_t)(m0 + row) * K + k0 + ss * 8, At + c * 2048 + w * 512);
            gl_lds16(B + (size_t)(n0 + row) * K + k0 + ss * 8, Bt + c * 2048 + w * 512);
        }
        __syncthreads();                         // compiler drains vmcnt before barrier
#pragma unroll
        for (int ks = 0; ks < 2; ++ks) {
            const int bc = ks * 64 + lk * 16;
            short8 af[4], bfr[4];
#pragma unroll
            for (int m = 0; m < 4; ++m) {
                int row = wm * 64 + m * 16 + l15;
                af[m] = *(const short8*)((char*)At + row * 128 + (bc ^ ((row & 7) << 4)));
            }
#pragma unroll
            for (int n = 0; n < 4; ++n) {
                int row = wn * 64 + n * 16 + l15;
                bfr[n] = *(const short8*)((char*)Bt + row * 128 + (bc ^ ((row & 7) << 4)));
            }
#pragma unroll
            for (int m = 0; m < 4; ++m)
#pragma unroll
                for (int n = 0; n < 4; ++n)
                    acc[m][n] = __builtin_amdgcn_mfma_f32_16x16x32_bf16(af[m], bfr[n], acc[m][n], 0, 0, 0);
        }
    }

    if (!isv) {
#pragma unroll
        for (int m = 0; m < 4; ++m)
#pragma unroll
            for (int n = 0; n < 4; ++n) {
                int col = n0 + wn * 64 + n * 16 + l15;
                float bv = ub[col];
#pragma unroll
                for (int r = 0; r < 4; ++r) {
                    int row = m0 + wm * 64 + m * 16 + lk * 4 + r;
                    Y[(size_t)row * 1024 + col] = f2bf(acc[m][n][r] + bv);
                }
            }
    } else {
#pragma unroll
        for (int m = 0; m < 4; ++m)
#pragma unroll
            for (int n = 0; n < 4; ++n) {
                int col = n0 + wn * 64 + n * 16 + l15;          // e index
                int row0 = m0 + wm * 64 + m * 16 + lk * 4;      // i index base
                short4v pk;
#pragma unroll
                for (int r = 0; r < 4; ++r) pk[r] = (short)f2bf(acc[m][n][r]);
                *(short4v*)(V2t + (size_t)col * 16384 + row0) = pk;
            }
    }
}

// ---------------- windowed causal attention, barrier-free fragment streaming ----------------
// One block = (window win, 32 q-rows). 4 waves, grid 512, LDS 17.4 KB.
// QK^T and PV read MFMA fragments DIRECTLY from global (y, xb, v2t are K-major;
// a fragment = 8 contiguous bf16/lane). Only softmax uses LDS (P + rmax/rsum).
__global__ __launch_bounds__(256, 4) void attn_win(
    const u16* __restrict__ y, const u16* __restrict__ xb,
    const u16* __restrict__ vt, const float* __restrict__ xres,
    const float* __restrict__ b2, float* __restrict__ outp)
{
    __shared__ __align__(16) char smem[17408];
    u16* P  = (u16*)smem;                      // [32][256] bf16, XOR-swizzled
    float* rmax = (float*)(smem + 16384);      // [32][4]
    float* rsum = (float*)(smem + 16896);      // [32][4]

    const int t = threadIdx.x;
    const int lane = t & 63, wv = t >> 6;
    const int l15 = lane & 15, lk = lane >> 4;
    const int bid = blockIdx.x;
    const int swz = (bid & 7) * 64 + (bid >> 3);
    const int win = swz >> 3, qc = swz & 7;
    const size_t qrow0 = (size_t)win * 256 + qc * 32;
    const size_t krow0 = (size_t)win * 256;

    f32x4 acc[2][4];
#pragma unroll
    for (int m = 0; m < 2; ++m)
#pragma unroll
        for (int n = 0; n < 4; ++n)
            acc[m][n] = (f32x4){0.f, 0.f, 0.f, 0.f};

    // ---- phase 1: scores = y @ x^T over E=1024 (no LDS, no barriers) ----
    for (int e0 = 0; e0 < 1024; e0 += 64) {
#pragma unroll
        for (int ks = 0; ks < 2; ++ks) {
            const int co = e0 + ks * 32 + lk * 8;
            short8 af[2], bfr[4];
#pragma unroll
            for (int m = 0; m < 2; ++m)
                af[m] = *(const short8*)(y + (qrow0 + m * 16 + l15) * 1024 + co);
#pragma unroll
            for (int n = 0; n < 4; ++n)
                bfr[n] = *(const short8*)(xb + (krow0 + wv * 64 + n * 16 + l15) * 1024 + co);
            __builtin_amdgcn_s_setprio(1);
#pragma unroll
            for (int m = 0; m < 2; ++m)
#pragma unroll
                for (int n = 0; n < 4; ++n)
                    acc[m][n] = __builtin_amdgcn_mfma_f32_16x16x32_bf16(af[m], bfr[n], acc[m][n], 0, 0, 0);
            __builtin_amdgcn_s_setprio(0);
        }
    }

    // ---- phase 2: register softmax ----
#pragma unroll
    for (int m = 0; m < 2; ++m)
#pragma unroll
        for (int n = 0; n < 4; ++n) {
            int col = wv * 64 + n * 16 + l15;
#pragma unroll
            for (int r = 0; r < 4; ++r) {
                int qpos = qc * 32 + m * 16 + lk * 4 + r;
                float v = acc[m][n][r] * 0.125f;
                acc[m][n][r] = (col <= qpos) ? v : -1e30f;
            }
        }
#pragma unroll
    for (int m = 0; m < 2; ++m)
#pragma unroll
        for (int r = 0; r < 4; ++r) {
            float tmx = fmaxf(fmaxf(acc[m][0][r], acc[m][1][r]), fmaxf(acc[m][2][r], acc[m][3][r]));
            tmx = fmaxf(tmx, __shfl_xor(tmx, 1));
            tmx = fmaxf(tmx, __shfl_xor(tmx, 2));
            tmx = fmaxf(tmx, __shfl_xor(tmx, 4));
            tmx = fmaxf(tmx, __shfl_xor(tmx, 8));
            if (l15 == 0) rmax[(m * 16 + lk * 4 + r) * 4 + wv] = tmx;
        }
    __syncthreads();
#pragma unroll
    for (int m = 0; m < 2; ++m)
#pragma unroll
        for (int r = 0; r < 4; ++r) {
            int row = m * 16 + lk * 4 + r;
            float m4 = fmaxf(fmaxf(rmax[row * 4], rmax[row * 4 + 1]),
                             fmaxf(rmax[row * 4 + 2], rmax[row * 4 + 3]));
            float s = 0.f;
#pragma unroll
            for (int n = 0; n < 4; ++n) {
                float e = __expf(acc[m][n][r] - m4);
                acc[m][n][r] = e;
                s += e;
            }
            s += __shfl_xor(s, 1);
            s += __shfl_xor(s, 2);
            s += __shfl_xor(s, 4);
            s += __shfl_xor(s, 8);
            if (l15 == 0) rsum[row * 4 + wv] = s;
        }
    __syncthreads();
#pragma unroll
    for (int m = 0; m < 2; ++m)
#pragma unroll
        for (int r = 0; r < 4; ++r) {
            int row = m * 16 + lk * 4 + r;
            float inv = 1.f / (rsum[row * 4] + rsum[row * 4 + 1] + rsum[row * 4 + 2] + rsum[row * 4 + 3]);
#pragma unroll
            for (int n = 0; n < 4; ++n) {
                int col = wv * 64 + n * 16 + l15;
                *(u16*)((char*)P + row * 512 + ((col * 2) ^ ((row & 7) << 4))) = f2bf(acc[m][n][r] * inv);
            }
        }
    __syncthreads();

    // hoist all P fragments to registers (P read exactly once)
    short8 pa[8][2];
#pragma unroll
    for (int ks = 0; ks < 8; ++ks)
#pragma unroll
        for (int m = 0; m < 2; ++m) {
            int row = m * 16 + l15;
            pa[ks][m] = *(const short8*)((char*)P + row * 512 + ((ks * 64 + lk * 16) ^ ((row & 7) << 4)));
        }

    // ---- phase 3: out = attn @ v2 + b2 + x (V fragments direct from global) ----
    for (int n0 = 0; n0 < 1024; n0 += 64) {
        f32x4 acc2[2];
#pragma unroll
        for (int m = 0; m < 2; ++m) acc2[m] = (f32x4){0.f, 0.f, 0.f, 0.f};
#pragma unroll
        for (int ks = 0; ks < 8; ++ks) {
            short8 bfr = *(const short8*)(vt + (size_t)(n0 + wv * 16 + l15) * 16384
                                             + win * 256 + ks * 32 + lk * 8);
            __builtin_amdgcn_s_setprio(1);
#pragma unroll
            for (int m = 0; m < 2; ++m)
                acc2[m] = __builtin_amdgcn_mfma_f32_16x16x32_bf16(pa[ks][m], bfr, acc2[m], 0, 0, 0);
            __builtin_amdgcn_s_setprio(0);
        }
#pragma unroll
        for (int m = 0; m < 2; ++m) {
#pragma unroll
            for (int r = 0; r < 4; ++r) {
                int row = m * 16 + lk * 4 + r;
                int col = n0 + wv * 16 + l15;
                size_t idx = (qrow0 + row) * 1024 + col;
                outp[idx] = acc2[m][r] + b2[col] + xres[idx];
            }
        }
    }
}

extern "C" void kernel_launch(void* const* d_in, const int* in_sizes, int n_in,
                              void* d_out, int out_size, void* d_ws, size_t ws_size,
                              hipStream_t stream) {
    const float* x  = (const float*)d_in[0];
    const float* Wq = (const float*)d_in[1];
    const float* bq = (const float*)d_in[2];
    const float* Wk = (const float*)d_in[3];
    // bk (d_in[4]) contributes only row-constants to scores -> cancels in softmax
    const float* Wv = (const float*)d_in[5];
    const float* bv = (const float*)d_in[6];
    const float* Wo = (const float*)d_in[7];
    const float* bo = (const float*)d_in[8];
    float* out = (float*)d_out;

    char* ws = (char*)d_ws;
    u16* xb  = (u16*)(ws);                    // [16384,1024] bf16
    u16* yb  = (u16*)(ws + 33554432);         // [16384,1024] bf16
    u16* v2t = (u16*)(ws + 67108864);         // [1024,16384] bf16 (v2 transposed)
    u16* WqT = (u16*)(ws + 100663296);        // [1024,1024] bf16
    u16* WkT = (u16*)(ws + 102760448);        // [1024,1024] bf16
    u16* WvT = (u16*)(ws + 104857600);        // [1024,1024] bf16
    u16* Wob = (u16*)(ws + 106954752);        // [1024,1024] bf16
    u16* Hb  = (u16*)(ws + 109051904);        // [1024,1024] bf16 H = Wk^T Wq
    u16* W2b = (u16*)(ws + 111149056);        // [1024,1024] bf16 W2 = Wo Wv
    float* u_  = (float*)(ws + 113246208);    // [1024] fp32
    float* b2_ = (float*)(ws + 113250304);    // [1024] fp32

    cast_f32_bf16<<<8192, 256, 0, stream>>>(x, xb, 16777216);
    wcast<<<1024, 256, 0, stream>>>(Wq, Wk, Wv, Wo, WqT, WkT, WvT, Wob);
    ub2<<<68, 256, 0, stream>>>(Wk, bq, Wo, bv, bo, u_, b2_);
    gemm_small_dual<<<512, 256, 0, stream>>>(WkT, WqT, Hb, Wob, WvT, W2b);
    gemm_yv<<<dim3(16, 128), 256, 0, stream>>>(xb, Hb, W2b, u_, yb, v2t);
    attn_win<<<512, 256, 0, stream>>>(yb, xb, v2t, x, b2_, out);
}

// Round 11
// 207.552 us; speedup vs baseline: 1.1400x; 1.1400x over previous
//
#include <hip/hip_runtime.h>
#include <hip/hip_bf16.h>

// LocalSelfAttention: B=4, S=4096, E=1024, WINDOW=256, SCALE=0.125
// Algebra: scores_ij = (x G + u)_i . x_j (row-consts cancel in softmax),
//   G = Wq^T Wk, u = Wk^T bq.  Since attn rows sum to 1:
//   out = attn @ (x W2^T) + b2 + x,  W2 = Wo Wv, b2 = Wo bv + bo.
// Round 11: revert to measured-best components: reg-staged gemm_yv (r9, 88us),
//   64-row LDS-staged attn (r6 structure, 58us) + v2t PV + fp32 epilogue.

typedef unsigned short u16;
typedef __attribute__((ext_vector_type(8))) short short8;   // 8 bf16
typedef __attribute__((ext_vector_type(4))) short short4v;  // 4 bf16 (8B)
typedef __attribute__((ext_vector_type(4))) float f32x4;

__device__ __forceinline__ u16 f2bf(float f) {
    __hip_bfloat16 h = __float2bfloat16(f);
    return __builtin_bit_cast(u16, h);
}

// ---------------- cast fp32 -> bf16, vectorized ----------------
__global__ void cast_f32_bf16(const float* __restrict__ src, u16* __restrict__ dst, int n) {
    int i = (blockIdx.x * 256 + threadIdx.x) * 8;
    if (i >= n) return;
    const float4* s = (const float4*)(src + i);
    float4 a = s[0], b = s[1];
    short8 o;
    o[0] = (short)f2bf(a.x); o[1] = (short)f2bf(a.y); o[2] = (short)f2bf(a.z); o[3] = (short)f2bf(a.w);
    o[4] = (short)f2bf(b.x); o[5] = (short)f2bf(b.y); o[6] = (short)f2bf(b.z); o[7] = (short)f2bf(b.w);
    *(short8*)(dst + i) = o;
}

// ---------------- weight casts: WqT, WkT, WvT (transposed), Wob (straight) ----------------
__global__ void wcast(const float* __restrict__ Wq, const float* __restrict__ Wk,
                      const float* __restrict__ Wv, const float* __restrict__ Wo,
                      u16* __restrict__ WqT, u16* __restrict__ WkT,
                      u16* __restrict__ WvT, u16* __restrict__ Wob)
{
    __shared__ float lt[64][65];
    const int which = blockIdx.x >> 8;
    const int bid = blockIdx.x & 255;
    const int c0 = (bid & 15) * 64, r0 = (bid >> 4) * 64;
    const int t = threadIdx.x;
    const int tr = t >> 3, tc = (t & 7) * 8;
    const float* src = which == 0 ? Wq : which == 1 ? Wk : which == 2 ? Wv : Wo;
    if (which == 3) {
#pragma unroll
        for (int p = 0; p < 2; ++p) {
            int r = p * 32 + tr;
            const float* s = src + (size_t)(r0 + r) * 1024 + c0 + tc;
            float4 a = *(const float4*)s, b = *(const float4*)(s + 4);
            short8 o;
            o[0] = (short)f2bf(a.x); o[1] = (short)f2bf(a.y); o[2] = (short)f2bf(a.z); o[3] = (short)f2bf(a.w);
            o[4] = (short)f2bf(b.x); o[5] = (short)f2bf(b.y); o[6] = (short)f2bf(b.z); o[7] = (short)f2bf(b.w);
            *(short8*)(Wob + (size_t)(r0 + r) * 1024 + c0 + tc) = o;
        }
        return;
    }
    u16* dst = which == 0 ? WqT : which == 1 ? WkT : WvT;
#pragma unroll
    for (int p = 0; p < 2; ++p) {
        int r = p * 32 + tr;
        const float* s = src + (size_t)(r0 + r) * 1024 + c0 + tc;
        float4 a = *(const float4*)s, b = *(const float4*)(s + 4);
        lt[r][tc + 0] = a.x; lt[r][tc + 1] = a.y; lt[r][tc + 2] = a.z; lt[r][tc + 3] = a.w;
        lt[r][tc + 4] = b.x; lt[r][tc + 5] = b.y; lt[r][tc + 6] = b.z; lt[r][tc + 7] = b.w;
    }
    __syncthreads();
#pragma unroll
    for (int p = 0; p < 2; ++p) {
        int r = p * 32 + tr;
        short8 o;
#pragma unroll
        for (int j = 0; j < 8; ++j) o[j] = (short)f2bf(lt[tc + j][r]);
        *(short8*)(dst + (size_t)(c0 + r) * 1024 + r0 + tc) = o;
    }
}

// ---------------- u = Wk^T bq ; b2 = Wo bv + bo (fp32) ----------------
__global__ void ub2(const float* __restrict__ Wk, const float* __restrict__ bq,
                    const float* __restrict__ Wo, const float* __restrict__ bv,
                    const float* __restrict__ bo, float* __restrict__ u, float* __restrict__ b2)
{
    const int t = threadIdx.x, bid = blockIdx.x;
    if (bid < 4) {
        int b = bid * 256 + t;
        float acc = 0.f;
        for (int o = 0; o < 1024; ++o) acc += Wk[(size_t)o * 1024 + b] * bq[o];
        u[b] = acc;
    } else {
        int n = (bid - 4) * 16 + (t >> 4);
        int l = t & 15;
        float acc = 0.f;
        for (int m = l; m < 1024; m += 16) acc += Wo[(size_t)n * 1024 + m] * bv[m];
#pragma unroll
        for (int s = 1; s < 16; s <<= 1) acc += __shfl_xor(acc, s, 64);
        if (l == 0) b2[n] = acc + bo[n];
    }
}

// ---------------- dual small GEMM (1024^3): H = WkT @ WqT^T, W2 = Wob @ WvT^T ----------------
__global__ __launch_bounds__(256, 4) void gemm_small_dual(
    const u16* __restrict__ HA, const u16* __restrict__ HB, u16* __restrict__ HC,
    const u16* __restrict__ WA, const u16* __restrict__ WB, u16* __restrict__ WC)
{
    __shared__ __align__(16) u16 At[64 * 64], Bt[64 * 64];
    const bool sec = blockIdx.x >= 256;
    const u16* A = sec ? WA : HA;
    const u16* B = sec ? WB : HB;
    u16* C = sec ? WC : HC;
    const int bid = blockIdx.x & 255;
    const int m0 = (bid >> 4) * 64, n0 = (bid & 15) * 64;
    const int t = threadIdx.x, lane = t & 63, w = t >> 6;
    const int l15 = lane & 15, lk = lane >> 4;

    f32x4 acc[4];
#pragma unroll
    for (int m = 0; m < 4; ++m) acc[m] = (f32x4){0.f, 0.f, 0.f, 0.f};

    for (int k0 = 0; k0 < 1024; k0 += 64) {
        __syncthreads();
#pragma unroll
        for (int p = 0; p < 2; ++p) {
            int e = p * 2048 + t * 8;
            int row = e >> 6, col = e & 63;
            short8 va = *(const short8*)(A + (size_t)(m0 + row) * 1024 + k0 + col);
            *(short8*)((char*)At + row * 128 + ((col * 2) ^ ((row & 7) << 4))) = va;
            short8 vb = *(const short8*)(B + (size_t)(n0 + row) * 1024 + k0 + col);
            *(short8*)((char*)Bt + row * 128 + ((col * 2) ^ ((row & 7) << 4))) = vb;
        }
        __syncthreads();
#pragma unroll
        for (int ks = 0; ks < 2; ++ks) {
            int bc = ks * 64 + lk * 16;
            int brow = w * 16 + l15;
            short8 bfr = *(const short8*)((char*)Bt + brow * 128 + (bc ^ ((brow & 7) << 4)));
#pragma unroll
            for (int m = 0; m < 4; ++m) {
                int arow = m * 16 + l15;
                short8 af = *(const short8*)((char*)At + arow * 128 + (bc ^ ((arow & 7) << 4)));
                acc[m] = __builtin_amdgcn_mfma_f32_16x16x32_bf16(af, bfr, acc[m], 0, 0, 0);
            }
        }
    }
#pragma unroll
    for (int m = 0; m < 4; ++m)
#pragma unroll
        for (int r = 0; r < 4; ++r) {
            int row = m0 + m * 16 + lk * 4 + r;
            int col = n0 + w * 16 + l15;
            C[(size_t)row * 1024 + col] = f2bf(acc[m][r]);
        }
}

// ---------------- fused dual GEMM: y = x@H + u ; v2t = (x@W2^T)^T ----------------
// 128^2 tile, 256 thr / 4 waves, reg-staged (r9-proven). Grid dim3(16,128).
__global__ __launch_bounds__(256, 2) void gemm_yv(
    const u16* __restrict__ A, const u16* __restrict__ BH, const u16* __restrict__ BW,
    const float* __restrict__ ub, u16* __restrict__ Y, u16* __restrict__ V2t)
{
    __shared__ __align__(16) u16 At[128 * 64];
    __shared__ __align__(16) u16 Bt[128 * 64];
    const int t = threadIdx.x;
    const int lane = t & 63;
    const int wid = t >> 6;
    const int wm = wid >> 1, wn = wid & 1;
    const int l15 = lane & 15, lk = lane >> 4;
    const int K = 1024;

    const int bid = blockIdx.y * gridDim.x + blockIdx.x;   // gridDim.x == 16
    const int cpx = 2048 >> 3;
    const int swz = (bid & 7) * cpx + (bid >> 3);
    const int tn = swz & 15;
    const int tm = swz >> 4;
    const int m0 = tm * 128;
    const bool isv = tn >= 8;
    const int n0 = (tn & 7) * 128;
    const u16* B = isv ? BW : BH;

    f32x4 acc[4][4];
#pragma unroll
    for (int m = 0; m < 4; ++m)
#pragma unroll
        for (int n = 0; n < 4; ++n)
            acc[m][n] = (f32x4){0.f, 0.f, 0.f, 0.f};

    for (int k0 = 0; k0 < K; k0 += 64) {
        __syncthreads();
#pragma unroll
        for (int p = 0; p < 4; ++p) {
            int e = p * 2048 + t * 8;
            int row = e >> 6, col = e & 63;
            short8 va = *(const short8*)(A + (size_t)(m0 + row) * K + k0 + col);
            *(short8*)((char*)At + row * 128 + ((col * 2) ^ ((row & 7) << 4))) = va;
            short8 vb = *(const short8*)(B + (size_t)(n0 + row) * K + k0 + col);
            *(short8*)((char*)Bt + row * 128 + ((col * 2) ^ ((row & 7) << 4))) = vb;
        }
        __syncthreads();
#pragma unroll
        for (int ks = 0; ks < 2; ++ks) {
            const int bc = ks * 64 + lk * 16;
            short8 af[4], bfr[4];
#pragma unroll
            for (int m = 0; m < 4; ++m) {
                int row = wm * 64 + m * 16 + l15;
                af[m] = *(const short8*)((char*)At + row * 128 + (bc ^ ((row & 7) << 4)));
            }
#pragma unroll
            for (int n = 0; n < 4; ++n) {
                int row = wn * 64 + n * 16 + l15;
                bfr[n] = *(const short8*)((char*)Bt + row * 128 + (bc ^ ((row & 7) << 4)));
            }
#pragma unroll
            for (int m = 0; m < 4; ++m)
#pragma unroll
                for (int n = 0; n < 4; ++n)
                    acc[m][n] = __builtin_amdgcn_mfma_f32_16x16x32_bf16(af[m], bfr[n], acc[m][n], 0, 0, 0);
        }
    }

    if (!isv) {
#pragma unroll
        for (int m = 0; m < 4; ++m)
#pragma unroll
            for (int n = 0; n < 4; ++n) {
                int col = n0 + wn * 64 + n * 16 + l15;
                float bv = ub[col];
#pragma unroll
                for (int r = 0; r < 4; ++r) {
                    int row = m0 + wm * 64 + m * 16 + lk * 4 + r;
                    Y[(size_t)row * 1024 + col] = f2bf(acc[m][n][r] + bv);
                }
            }
    } else {
#pragma unroll
        for (int m = 0; m < 4; ++m)
#pragma unroll
            for (int n = 0; n < 4; ++n) {
                int col = n0 + wn * 64 + n * 16 + l15;          // e index
                int row0 = m0 + wm * 64 + m * 16 + lk * 4;      // i index base
                short4v pk;
#pragma unroll
                for (int r = 0; r < 4; ++r) pk[r] = (short)f2bf(acc[m][n][r]);
                *(short4v*)(V2t + (size_t)col * 16384 + row0) = pk;
            }
    }
}

// ---------------- windowed causal attention (64-row blocks, r6 structure) ----------------
// One block = (window win, 64 q-rows). 4 waves, grid 256, LDS 75776 -> 2 blocks/CU.
// Phase 3 consumes v2t; epilogue: out = PV + b2 + x (fp32).
__global__ __launch_bounds__(256, 2) void attn_win(
    const u16* __restrict__ y, const u16* __restrict__ xb,
    const u16* __restrict__ vt, const float* __restrict__ xres,
    const float* __restrict__ b2, float* __restrict__ outp)
{
    // [0,8192) Qt | [8192,40960) Kt  (phase 1)
    // [0,32768) Vl                   (phase 3)
    // [40960,73728) P bf16 [64][256] swizzled
    // [73728,74752) rmax [64][4] | [74752,75776) rsum [64][4]
    __shared__ __align__(16) char smem[75776];
    u16* Qt = (u16*)smem;
    u16* Kt = (u16*)(smem + 8192);
    u16* Vl = (u16*)smem;
    u16* P  = (u16*)(smem + 40960);
    float* rmax = (float*)(smem + 73728);
    float* rsum = (float*)(smem + 74752);

    const int t = threadIdx.x;
    const int lane = t & 63, wv = t >> 6;
    const int l15 = lane & 15, lk = lane >> 4;
    const int bid = blockIdx.x;
    const int swz = (bid & 7) * 32 + (bid >> 3);
    const int win = swz >> 2, qc = swz & 3;
    const size_t qrow0 = (size_t)win * 256 + qc * 64;
    const size_t krow0 = (size_t)win * 256;

    f32x4 acc[4][4];
#pragma unroll
    for (int m = 0; m < 4; ++m)
#pragma unroll
        for (int n = 0; n < 4; ++n)
            acc[m][n] = (f32x4){0.f, 0.f, 0.f, 0.f};

    // ---- phase 1: scores = y @ x^T over E=1024 ----
    for (int e0 = 0; e0 < 1024; e0 += 64) {
        __syncthreads();
#pragma unroll
        for (int p = 0; p < 2; ++p) {  // Q tile 64x64 from y
            int e = p * 2048 + t * 8;
            int row = e >> 6, col = e & 63;
            short8 v = *(const short8*)(y + (qrow0 + row) * 1024 + e0 + col);
            *(short8*)((char*)Qt + row * 128 + ((col * 2) ^ ((row & 7) << 4))) = v;
        }
#pragma unroll
        for (int p = 0; p < 8; ++p) {  // K tile 256x64 from x
            int e = p * 2048 + t * 8;
            int row = e >> 6, col = e & 63;
            short8 v = *(const short8*)(xb + (krow0 + row) * 1024 + e0 + col);
            *(short8*)((char*)Kt + row * 128 + ((col * 2) ^ ((row & 7) << 4))) = v;
        }
        __syncthreads();
#pragma unroll
        for (int ks = 0; ks < 2; ++ks) {
            const int bc = ks * 64 + lk * 16;
            short8 af[4], bfr[4];
#pragma unroll
            for (int m = 0; m < 4; ++m) {
                int row = m * 16 + l15;
                af[m] = *(const short8*)((char*)Qt + row * 128 + (bc ^ ((row & 7) << 4)));
            }
#pragma unroll
            for (int n = 0; n < 4; ++n) {
                int row = wv * 64 + n * 16 + l15;
                bfr[n] = *(const short8*)((char*)Kt + row * 128 + (bc ^ ((row & 7) << 4)));
            }
            __builtin_amdgcn_s_setprio(1);
#pragma unroll
            for (int m = 0; m < 4; ++m)
#pragma unroll
                for (int n = 0; n < 4; ++n)
                    acc[m][n] = __builtin_amdgcn_mfma_f32_16x16x32_bf16(af[m], bfr[n], acc[m][n], 0, 0, 0);
            __builtin_amdgcn_s_setprio(0);
        }
    }

    // ---- phase 2: register softmax ----
#pragma unroll
    for (int m = 0; m < 4; ++m)
#pragma unroll
        for (int n = 0; n < 4; ++n) {
            int col = wv * 64 + n * 16 + l15;
#pragma unroll
            for (int r = 0; r < 4; ++r) {
                int qpos = qc * 64 + m * 16 + lk * 4 + r;
                float v = acc[m][n][r] * 0.125f;
                acc[m][n][r] = (col <= qpos) ? v : -1e30f;
            }
        }
#pragma unroll
    for (int m = 0; m < 4; ++m)
#pragma unroll
        for (int r = 0; r < 4; ++r) {
            float tmx = fmaxf(fmaxf(acc[m][0][r], acc[m][1][r]), fmaxf(acc[m][2][r], acc[m][3][r]));
            tmx = fmaxf(tmx, __shfl_xor(tmx, 1));
            tmx = fmaxf(tmx, __shfl_xor(tmx, 2));
            tmx = fmaxf(tmx, __shfl_xor(tmx, 4));
            tmx = fmaxf(tmx, __shfl_xor(tmx, 8));
            if (l15 == 0) rmax[(m * 16 + lk * 4 + r) * 4 + wv] = tmx;
        }
    __syncthreads();
#pragma unroll
    for (int m = 0; m < 4; ++m)
#pragma unroll
        for (int r = 0; r < 4; ++r) {
            int row = m * 16 + lk * 4 + r;
            float m4 = fmaxf(fmaxf(rmax[row * 4], rmax[row * 4 + 1]),
                             fmaxf(rmax[row * 4 + 2], rmax[row * 4 + 3]));
            float s = 0.f;
#pragma unroll
            for (int n = 0; n < 4; ++n) {
                float e = __expf(acc[m][n][r] - m4);
                acc[m][n][r] = e;
                s += e;
            }
            s += __shfl_xor(s, 1);
            s += __shfl_xor(s, 2);
            s += __shfl_xor(s, 4);
            s += __shfl_xor(s, 8);
            if (l15 == 0) rsum[row * 4 + wv] = s;
        }
    __syncthreads();
#pragma unroll
    for (int m = 0; m < 4; ++m)
#pragma unroll
        for (int r = 0; r < 4; ++r) {
            int row = m * 16 + lk * 4 + r;
            float inv = 1.f / (rsum[row * 4] + rsum[row * 4 + 1] + rsum[row * 4 + 2] + rsum[row * 4 + 3]);
#pragma unroll
            for (int n = 0; n < 4; ++n) {
                int col = wv * 64 + n * 16 + l15;
                *(u16*)((char*)P + row * 512 + ((col * 2) ^ ((row & 7) << 4))) = f2bf(acc[m][n][r] * inv);
            }
        }

    // ---- phase 3: out = attn @ v2 + b2 + x  via v2t [1024, 16384] ----
    for (int n0 = 0; n0 < 1024; n0 += 64) {
        __syncthreads();
#pragma unroll
        for (int p = 0; p < 8; ++p) {  // Vl 64(e) x 256(k)
            int e = p * 2048 + t * 8;
            int row = e >> 8, col = e & 255;
            short8 v = *(const short8*)(vt + (size_t)(n0 + row) * 16384 + win * 256 + col);
            *(short8*)((char*)Vl + row * 512 + ((col * 2) ^ ((row & 7) << 4))) = v;
        }
        __syncthreads();
        f32x4 acc2[4];
#pragma unroll
        for (int m = 0; m < 4; ++m) acc2[m] = (f32x4){0.f, 0.f, 0.f, 0.f};
#pragma unroll
        for (int ks = 0; ks < 8; ++ks) {
            const int bc = ks * 64 + lk * 16;
            short8 af[4];
#pragma unroll
            for (int m = 0; m < 4; ++m) {
                int row = m * 16 + l15;
                af[m] = *(const short8*)((char*)P + row * 512 + (bc ^ ((row & 7) << 4)));
            }
            int vrow = wv * 16 + l15;
            short8 bfr = *(const short8*)((char*)Vl + vrow * 512 + (bc ^ ((vrow & 7) << 4)));
            __builtin_amdgcn_s_setprio(1);
#pragma unroll
            for (int m = 0; m < 4; ++m)
                acc2[m] = __builtin_amdgcn_mfma_f32_16x16x32_bf16(af[m], bfr, acc2[m], 0, 0, 0);
            __builtin_amdgcn_s_setprio(0);
        }
#pragma unroll
        for (int m = 0; m < 4; ++m) {
#pragma unroll
            for (int r = 0; r < 4; ++r) {
                int row = m * 16 + lk * 4 + r;
                int col = n0 + wv * 16 + l15;
                size_t idx = (qrow0 + row) * 1024 + col;
                outp[idx] = acc2[m][r] + b2[col] + xres[idx];
            }
        }
    }
}

extern "C" void kernel_launch(void* const* d_in, const int* in_sizes, int n_in,
                              void* d_out, int out_size, void* d_ws, size_t ws_size,
                              hipStream_t stream) {
    const float* x  = (const float*)d_in[0];
    const float* Wq = (const float*)d_in[1];
    const float* bq = (const float*)d_in[2];
    const float* Wk = (const float*)d_in[3];
    // bk (d_in[4]) contributes only row-constants to scores -> cancels in softmax
    const float* Wv = (const float*)d_in[5];
    const float* bv = (const float*)d_in[6];
    const float* Wo = (const float*)d_in[7];
    const float* bo = (const float*)d_in[8];
    float* out = (float*)d_out;

    char* ws = (char*)d_ws;
    u16* xb  = (u16*)(ws);                    // [16384,1024] bf16
    u16* yb  = (u16*)(ws + 33554432);         // [16384,1024] bf16
    u16* v2t = (u16*)(ws + 67108864);         // [1024,16384] bf16 (v2 transposed)
    u16* WqT = (u16*)(ws + 100663296);        // [1024,1024] bf16
    u16* WkT = (u16*)(ws + 102760448);        // [1024,1024] bf16
    u16* WvT = (u16*)(ws + 104857600);        // [1024,1024] bf16
    u16* Wob = (u16*)(ws + 106954752);        // [1024,1024] bf16
    u16* Hb  = (u16*)(ws + 109051904);        // [1024,1024] bf16 H = Wk^T Wq
    u16* W2b = (u16*)(ws + 111149056);        // [1024,1024] bf16 W2 = Wo Wv
    float* u_  = (float*)(ws + 113246208);    // [1024] fp32
    float* b2_ = (float*)(ws + 113250304);    // [1024] fp32

    cast_f32_bf16<<<8192, 256, 0, stream>>>(x, xb, 16777216);
    wcast<<<1024, 256, 0, stream>>>(Wq, Wk, Wv, Wo, WqT, WkT, WvT, Wob);
    ub2<<<68, 256, 0, stream>>>(Wk, bq, Wo, bv, bo, u_, b2_);
    gemm_small_dual<<<512, 256, 0, stream>>>(WkT, WqT, Hb, Wob, WvT, W2b);
    gemm_yv<<<dim3(16, 128), 256, 0, stream>>>(xb, Hb, W2b, u_, yb, v2t);
    attn_win<<<256, 256, 0, stream>>>(yb, xb, v2t, x, b2_, out);
}

// Round 12
// 198.248 us; speedup vs baseline: 1.1935x; 1.0469x over previous
//
#include <hip/hip_runtime.h>
#include <hip/hip_bf16.h>

// LocalSelfAttention: B=4, S=4096, E=1024, WINDOW=256, SCALE=0.125
// Algebra: scores_ij = (x G + u)_i . x_j (row-consts cancel in softmax),
//   G = Wq^T Wk, u = Wk^T bq.  Since attn rows sum to 1:
//   out = attn @ (x W2^T) + b2 + x,  W2 = Wo Wv, b2 = Wo bv + bo.
// Round 12: attn phases 1&3 double-buffered with issue-early register prefetch
//   (T14): global loads for chunk i+2 fly while chunk i+1 is ds-written and
//   chunk i is consumed by MFMA. One barrier/iter. LDS 114KB, 1 block/CU.

typedef unsigned short u16;
typedef __attribute__((ext_vector_type(8))) short short8;   // 8 bf16
typedef __attribute__((ext_vector_type(4))) short short4v;  // 4 bf16 (8B)
typedef __attribute__((ext_vector_type(4))) float f32x4;

__device__ __forceinline__ u16 f2bf(float f) {
    __hip_bfloat16 h = __float2bfloat16(f);
    return __builtin_bit_cast(u16, h);
}

// ---------------- cast fp32 -> bf16, vectorized ----------------
__global__ void cast_f32_bf16(const float* __restrict__ src, u16* __restrict__ dst, int n) {
    int i = (blockIdx.x * 256 + threadIdx.x) * 8;
    if (i >= n) return;
    const float4* s = (const float4*)(src + i);
    float4 a = s[0], b = s[1];
    short8 o;
    o[0] = (short)f2bf(a.x); o[1] = (short)f2bf(a.y); o[2] = (short)f2bf(a.z); o[3] = (short)f2bf(a.w);
    o[4] = (short)f2bf(b.x); o[5] = (short)f2bf(b.y); o[6] = (short)f2bf(b.z); o[7] = (short)f2bf(b.w);
    *(short8*)(dst + i) = o;
}

// ---------------- weight casts: WqT, WkT, WvT (transposed), Wob (straight) ----------------
__global__ void wcast(const float* __restrict__ Wq, const float* __restrict__ Wk,
                      const float* __restrict__ Wv, const float* __restrict__ Wo,
                      u16* __restrict__ WqT, u16* __restrict__ WkT,
                      u16* __restrict__ WvT, u16* __restrict__ Wob)
{
    __shared__ float lt[64][65];
    const int which = blockIdx.x >> 8;
    const int bid = blockIdx.x & 255;
    const int c0 = (bid & 15) * 64, r0 = (bid >> 4) * 64;
    const int t = threadIdx.x;
    const int tr = t >> 3, tc = (t & 7) * 8;
    const float* src = which == 0 ? Wq : which == 1 ? Wk : which == 2 ? Wv : Wo;
    if (which == 3) {
#pragma unroll
        for (int p = 0; p < 2; ++p) {
            int r = p * 32 + tr;
            const float* s = src + (size_t)(r0 + r) * 1024 + c0 + tc;
            float4 a = *(const float4*)s, b = *(const float4*)(s + 4);
            short8 o;
            o[0] = (short)f2bf(a.x); o[1] = (short)f2bf(a.y); o[2] = (short)f2bf(a.z); o[3] = (short)f2bf(a.w);
            o[4] = (short)f2bf(b.x); o[5] = (short)f2bf(b.y); o[6] = (short)f2bf(b.z); o[7] = (short)f2bf(b.w);
            *(short8*)(Wob + (size_t)(r0 + r) * 1024 + c0 + tc) = o;
        }
        return;
    }
    u16* dst = which == 0 ? WqT : which == 1 ? WkT : WvT;
#pragma unroll
    for (int p = 0; p < 2; ++p) {
        int r = p * 32 + tr;
        const float* s = src + (size_t)(r0 + r) * 1024 + c0 + tc;
        float4 a = *(const float4*)s, b = *(const float4*)(s + 4);
        lt[r][tc + 0] = a.x; lt[r][tc + 1] = a.y; lt[r][tc + 2] = a.z; lt[r][tc + 3] = a.w;
        lt[r][tc + 4] = b.x; lt[r][tc + 5] = b.y; lt[r][tc + 6] = b.z; lt[r][tc + 7] = b.w;
    }
    __syncthreads();
#pragma unroll
    for (int p = 0; p < 2; ++p) {
        int r = p * 32 + tr;
        short8 o;
#pragma unroll
        for (int j = 0; j < 8; ++j) o[j] = (short)f2bf(lt[tc + j][r]);
        *(short8*)(dst + (size_t)(c0 + r) * 1024 + r0 + tc) = o;
    }
}

// ---------------- u = Wk^T bq ; b2 = Wo bv + bo (fp32) ----------------
__global__ void ub2(const float* __restrict__ Wk, const float* __restrict__ bq,
                    const float* __restrict__ Wo, const float* __restrict__ bv,
                    const float* __restrict__ bo, float* __restrict__ u, float* __restrict__ b2)
{
    const int t = threadIdx.x, bid = blockIdx.x;
    if (bid < 4) {
        int b = bid * 256 + t;
        float acc = 0.f;
        for (int o = 0; o < 1024; ++o) acc += Wk[(size_t)o * 1024 + b] * bq[o];
        u[b] = acc;
    } else {
        int n = (bid - 4) * 16 + (t >> 4);
        int l = t & 15;
        float acc = 0.f;
        for (int m = l; m < 1024; m += 16) acc += Wo[(size_t)n * 1024 + m] * bv[m];
#pragma unroll
        for (int s = 1; s < 16; s <<= 1) acc += __shfl_xor(acc, s, 64);
        if (l == 0) b2[n] = acc + bo[n];
    }
}

// ---------------- dual small GEMM (1024^3): H = WkT @ WqT^T, W2 = Wob @ WvT^T ----------------
__global__ __launch_bounds__(256, 4) void gemm_small_dual(
    const u16* __restrict__ HA, const u16* __restrict__ HB, u16* __restrict__ HC,
    const u16* __restrict__ WA, const u16* __restrict__ WB, u16* __restrict__ WC)
{
    __shared__ __align__(16) u16 At[64 * 64], Bt[64 * 64];
    const bool sec = blockIdx.x >= 256;
    const u16* A = sec ? WA : HA;
    const u16* B = sec ? WB : HB;
    u16* C = sec ? WC : HC;
    const int bid = blockIdx.x & 255;
    const int m0 = (bid >> 4) * 64, n0 = (bid & 15) * 64;
    const int t = threadIdx.x, lane = t & 63, w = t >> 6;
    const int l15 = lane & 15, lk = lane >> 4;

    f32x4 acc[4];
#pragma unroll
    for (int m = 0; m < 4; ++m) acc[m] = (f32x4){0.f, 0.f, 0.f, 0.f};

    for (int k0 = 0; k0 < 1024; k0 += 64) {
        __syncthreads();
#pragma unroll
        for (int p = 0; p < 2; ++p) {
            int e = p * 2048 + t * 8;
            int row = e >> 6, col = e & 63;
            short8 va = *(const short8*)(A + (size_t)(m0 + row) * 1024 + k0 + col);
            *(short8*)((char*)At + row * 128 + ((col * 2) ^ ((row & 7) << 4))) = va;
            short8 vb = *(const short8*)(B + (size_t)(n0 + row) * 1024 + k0 + col);
            *(short8*)((char*)Bt + row * 128 + ((col * 2) ^ ((row & 7) << 4))) = vb;
        }
        __syncthreads();
#pragma unroll
        for (int ks = 0; ks < 2; ++ks) {
            int bc = ks * 64 + lk * 16;
            int brow = w * 16 + l15;
            short8 bfr = *(const short8*)((char*)Bt + brow * 128 + (bc ^ ((brow & 7) << 4)));
#pragma unroll
            for (int m = 0; m < 4; ++m) {
                int arow = m * 16 + l15;
                short8 af = *(const short8*)((char*)At + arow * 128 + (bc ^ ((arow & 7) << 4)));
                acc[m] = __builtin_amdgcn_mfma_f32_16x16x32_bf16(af, bfr, acc[m], 0, 0, 0);
            }
        }
    }
#pragma unroll
    for (int m = 0; m < 4; ++m)
#pragma unroll
        for (int r = 0; r < 4; ++r) {
            int row = m0 + m * 16 + lk * 4 + r;
            int col = n0 + w * 16 + l15;
            C[(size_t)row * 1024 + col] = f2bf(acc[m][r]);
        }
}

// ---------------- fused dual GEMM: y = x@H + u ; v2t = (x@W2^T)^T ----------------
// 128^2 tile, 256 thr / 4 waves, reg-staged (r9-proven). Grid dim3(16,128).
__global__ __launch_bounds__(256, 2) void gemm_yv(
    const u16* __restrict__ A, const u16* __restrict__ BH, const u16* __restrict__ BW,
    const float* __restrict__ ub, u16* __restrict__ Y, u16* __restrict__ V2t)
{
    __shared__ __align__(16) u16 At[128 * 64];
    __shared__ __align__(16) u16 Bt[128 * 64];
    const int t = threadIdx.x;
    const int lane = t & 63;
    const int wid = t >> 6;
    const int wm = wid >> 1, wn = wid & 1;
    const int l15 = lane & 15, lk = lane >> 4;
    const int K = 1024;

    const int bid = blockIdx.y * gridDim.x + blockIdx.x;   // gridDim.x == 16
    const int cpx = 2048 >> 3;
    const int swz = (bid & 7) * cpx + (bid >> 3);
    const int tn = swz & 15;
    const int tm = swz >> 4;
    const int m0 = tm * 128;
    const bool isv = tn >= 8;
    const int n0 = (tn & 7) * 128;
    const u16* B = isv ? BW : BH;

    f32x4 acc[4][4];
#pragma unroll
    for (int m = 0; m < 4; ++m)
#pragma unroll
        for (int n = 0; n < 4; ++n)
            acc[m][n] = (f32x4){0.f, 0.f, 0.f, 0.f};

    for (int k0 = 0; k0 < K; k0 += 64) {
        __syncthreads();
#pragma unroll
        for (int p = 0; p < 4; ++p) {
            int e = p * 2048 + t * 8;
            int row = e >> 6, col = e & 63;
            short8 va = *(const short8*)(A + (size_t)(m0 + row) * K + k0 + col);
            *(short8*)((char*)At + row * 128 + ((col * 2) ^ ((row & 7) << 4))) = va;
            short8 vb = *(const short8*)(B + (size_t)(n0 + row) * K + k0 + col);
            *(short8*)((char*)Bt + row * 128 + ((col * 2) ^ ((row & 7) << 4))) = vb;
        }
        __syncthreads();
#pragma unroll
        for (int ks = 0; ks < 2; ++ks) {
            const int bc = ks * 64 + lk * 16;
            short8 af[4], bfr[4];
#pragma unroll
            for (int m = 0; m < 4; ++m) {
                int row = wm * 64 + m * 16 + l15;
                af[m] = *(const short8*)((char*)At + row * 128 + (bc ^ ((row & 7) << 4)));
            }
#pragma unroll
            for (int n = 0; n < 4; ++n) {
                int row = wn * 64 + n * 16 + l15;
                bfr[n] = *(const short8*)((char*)Bt + row * 128 + (bc ^ ((row & 7) << 4)));
            }
#pragma unroll
            for (int m = 0; m < 4; ++m)
#pragma unroll
                for (int n = 0; n < 4; ++n)
                    acc[m][n] = __builtin_amdgcn_mfma_f32_16x16x32_bf16(af[m], bfr[n], acc[m][n], 0, 0, 0);
        }
    }

    if (!isv) {
#pragma unroll
        for (int m = 0; m < 4; ++m)
#pragma unroll
            for (int n = 0; n < 4; ++n) {
                int col = n0 + wn * 64 + n * 16 + l15;
                float bv = ub[col];
#pragma unroll
                for (int r = 0; r < 4; ++r) {
                    int row = m0 + wm * 64 + m * 16 + lk * 4 + r;
                    Y[(size_t)row * 1024 + col] = f2bf(acc[m][n][r] + bv);
                }
            }
    } else {
#pragma unroll
        for (int m = 0; m < 4; ++m)
#pragma unroll
            for (int n = 0; n < 4; ++n) {
                int col = n0 + wn * 64 + n * 16 + l15;          // e index
                int row0 = m0 + wm * 64 + m * 16 + lk * 4;      // i index base
                short4v pk;
#pragma unroll
                for (int r = 0; r < 4; ++r) pk[r] = (short)f2bf(acc[m][n][r]);
                *(short4v*)(V2t + (size_t)col * 16384 + row0) = pk;
            }
    }
}

// ---------------- windowed causal attention, double-buffered staging (T14) ----------------
// One block = (window win, 64 q-rows). 4 waves, grid 256, LDS 116736 -> 1 block/CU.
// Pipeline: regs prefetch chunk i+2 while chunk i+1 is ds-written to buf^1 and
// chunk i is consumed by MFMA. One barrier per iter.
// Safety ledger: WRITE(b^1) at iter i touches the buffer consumed in iter i-1;
// the barrier at the END of iter i-1 guarantees all waves finished those reads.
// Reads of buf b at iter i see writes from iter i-1 (barrier's lgkm drain).
__global__ __launch_bounds__(256, 1) void attn_win(
    const u16* __restrict__ y, const u16* __restrict__ xb,
    const u16* __restrict__ vt, const float* __restrict__ xres,
    const float* __restrict__ b2, float* __restrict__ outp)
{
    // [0,81920): staging dbuf, buf b at b*40960: Qt 8KB + Kt 32KB (phase1) / Vl 32KB (phase3)
    // [81920,114688): P bf16 [64][256] swizzled
    // [114688,115712): rmax [64][4] | [115712,116736): rsum [64][4]
    __shared__ __align__(16) char smem[116736];
    u16* P  = (u16*)(smem + 81920);
    float* rmax = (float*)(smem + 114688);
    float* rsum = (float*)(smem + 115712);

    const int t = threadIdx.x;
    const int lane = t & 63, wv = t >> 6;
    const int l15 = lane & 15, lk = lane >> 4;
    const int bid = blockIdx.x;
    const int swz = (bid & 7) * 32 + (bid >> 3);
    const int win = swz >> 2, qc = swz & 3;
    const size_t qrow0 = (size_t)win * 256 + qc * 64;
    const size_t krow0 = (size_t)win * 256;

    f32x4 acc[4][4];
#pragma unroll
    for (int m = 0; m < 4; ++m)
#pragma unroll
        for (int n = 0; n < 4; ++n)
            acc[m][n] = (f32x4){0.f, 0.f, 0.f, 0.f};

    // ---- phase 1: scores = y @ x^T over E=1024, 16 chunks, 2-deep pipeline ----
    short8 pq[2], pk[8];
    auto LOAD_QK = [&](int e0) {
#pragma unroll
        for (int p = 0; p < 2; ++p) {
            int e = p * 2048 + t * 8;
            pq[p] = *(const short8*)(y + (qrow0 + (e >> 6)) * 1024 + e0 + (e & 63));
        }
#pragma unroll
        for (int p = 0; p < 8; ++p) {
            int e = p * 2048 + t * 8;
            pk[p] = *(const short8*)(xb + (krow0 + (e >> 6)) * 1024 + e0 + (e & 63));
        }
    };
    auto WRITE_QK = [&](int b) {
        char* Qt = smem + b * 40960;
        char* Kt = Qt + 8192;
#pragma unroll
        for (int p = 0; p < 2; ++p) {
            int e = p * 2048 + t * 8;
            int row = e >> 6, col = e & 63;
            *(short8*)(Qt + row * 128 + ((col * 2) ^ ((row & 7) << 4))) = pq[p];
        }
#pragma unroll
        for (int p = 0; p < 8; ++p) {
            int e = p * 2048 + t * 8;
            int row = e >> 6, col = e & 63;
            *(short8*)(Kt + row * 128 + ((col * 2) ^ ((row & 7) << 4))) = pk[p];
        }
    };

    LOAD_QK(0);
    WRITE_QK(0);
    LOAD_QK(64);
    __syncthreads();

    for (int i = 0; i < 16; ++i) {
        const int b = i & 1;
        if (i + 1 < 16) {
            WRITE_QK(b ^ 1);             // chunk i+1 (in regs) -> other buffer
            if (i + 2 < 16) LOAD_QK((i + 2) * 64);
        }
        const char* Qt = smem + b * 40960;
        const char* Kt = Qt + 8192;
#pragma unroll
        for (int ks = 0; ks < 2; ++ks) {
            const int bc = ks * 64 + lk * 16;
            short8 af[4], bfr[4];
#pragma unroll
            for (int m = 0; m < 4; ++m) {
                int row = m * 16 + l15;
                af[m] = *(const short8*)(Qt + row * 128 + (bc ^ ((row & 7) << 4)));
            }
#pragma unroll
            for (int n = 0; n < 4; ++n) {
                int row = wv * 64 + n * 16 + l15;
                bfr[n] = *(const short8*)(Kt + row * 128 + (bc ^ ((row & 7) << 4)));
            }
            __builtin_amdgcn_s_setprio(1);
#pragma unroll
            for (int m = 0; m < 4; ++m)
#pragma unroll
                for (int n = 0; n < 4; ++n)
                    acc[m][n] = __builtin_amdgcn_mfma_f32_16x16x32_bf16(af[m], bfr[n], acc[m][n], 0, 0, 0);
            __builtin_amdgcn_s_setprio(0);
        }
        __syncthreads();
    }

    // ---- phase 2: register softmax ----
#pragma unroll
    for (int m = 0; m < 4; ++m)
#pragma unroll
        for (int n = 0; n < 4; ++n) {
            int col = wv * 64 + n * 16 + l15;
#pragma unroll
            for (int r = 0; r < 4; ++r) {
                int qpos = qc * 64 + m * 16 + lk * 4 + r;
                float v = acc[m][n][r] * 0.125f;
                acc[m][n][r] = (col <= qpos) ? v : -1e30f;
            }
        }
#pragma unroll
    for (int m = 0; m < 4; ++m)
#pragma unroll
        for (int r = 0; r < 4; ++r) {
            float tmx = fmaxf(fmaxf(acc[m][0][r], acc[m][1][r]), fmaxf(acc[m][2][r], acc[m][3][r]));
            tmx = fmaxf(tmx, __shfl_xor(tmx, 1));
            tmx = fmaxf(tmx, __shfl_xor(tmx, 2));
            tmx = fmaxf(tmx, __shfl_xor(tmx, 4));
            tmx = fmaxf(tmx, __shfl_xor(tmx, 8));
            if (l15 == 0) rmax[(m * 16 + lk * 4 + r) * 4 + wv] = tmx;
        }
    __syncthreads();
#pragma unroll
    for (int m = 0; m < 4; ++m)
#pragma unroll
        for (int r = 0; r < 4; ++r) {
            int row = m * 16 + lk * 4 + r;
            float m4 = fmaxf(fmaxf(rmax[row * 4], rmax[row * 4 + 1]),
                             fmaxf(rmax[row * 4 + 2], rmax[row * 4 + 3]));
            float s = 0.f;
#pragma unroll
            for (int n = 0; n < 4; ++n) {
                float e = __expf(acc[m][n][r] - m4);
                acc[m][n][r] = e;
                s += e;
            }
            s += __shfl_xor(s, 1);
            s += __shfl_xor(s, 2);
            s += __shfl_xor(s, 4);
            s += __shfl_xor(s, 8);
            if (l15 == 0) rsum[row * 4 + wv] = s;
        }
    __syncthreads();
#pragma unroll
    for (int m = 0; m < 4; ++m)
#pragma unroll
        for (int r = 0; r < 4; ++r) {
            int row = m * 16 + lk * 4 + r;
            float inv = 1.f / (rsum[row * 4] + rsum[row * 4 + 1] + rsum[row * 4 + 2] + rsum[row * 4 + 3]);
#pragma unroll
            for (int n = 0; n < 4; ++n) {
                int col = wv * 64 + n * 16 + l15;
                *(u16*)((char*)P + row * 512 + ((col * 2) ^ ((row & 7) << 4))) = f2bf(acc[m][n][r] * inv);
            }
        }

    // ---- phase 3: out = attn @ v2 + b2 + x, 16 chunks, 2-deep pipeline ----
    short8 pv[8];
    auto LOAD_V = [&](int n0) {
#pragma unroll
        for (int p = 0; p < 8; ++p) {
            int e = p * 2048 + t * 8;
            pv[p] = *(const short8*)(vt + (size_t)(n0 + (e >> 8)) * 16384 + win * 256 + (e & 255));
        }
    };
    auto WRITE_V = [&](int b) {
        char* Vl = smem + b * 40960;
#pragma unroll
        for (int p = 0; p < 8; ++p) {
            int e = p * 2048 + t * 8;
            int row = e >> 8, col = e & 255;
            *(short8*)(Vl + row * 512 + ((col * 2) ^ ((row & 7) << 4))) = pv[p];
        }
    };

    LOAD_V(0);
    WRITE_V(0);        // staging region: all phase-1 reads finished before softmax barriers
    LOAD_V(64);
    __syncthreads();   // P writes + Vl buf0 visible

    for (int i = 0; i < 16; ++i) {
        const int b = i & 1;
        const int n0 = i * 64;
        if (i + 1 < 16) {
            WRITE_V(b ^ 1);
            if (i + 2 < 16) LOAD_V((i + 2) * 64);
        }
        const char* Vl = smem + b * 40960;
        f32x4 acc2[4];
#pragma unroll
        for (int m = 0; m < 4; ++m) acc2[m] = (f32x4){0.f, 0.f, 0.f, 0.f};
#pragma unroll
        for (int ks = 0; ks < 8; ++ks) {
            const int bc = ks * 64 + lk * 16;
            short8 af[4];
#pragma unroll
            for (int m = 0; m < 4; ++m) {
                int row = m * 16 + l15;
                af[m] = *(const short8*)((char*)P + row * 512 + (bc ^ ((row & 7) << 4)));
            }
            int vrow = wv * 16 + l15;
            short8 bfr = *(const short8*)(Vl + vrow * 512 + (bc ^ ((vrow & 7) << 4)));
            __builtin_amdgcn_s_setprio(1);
#pragma unroll
            for (int m = 0; m < 4; ++m)
                acc2[m] = __builtin_amdgcn_mfma_f32_16x16x32_bf16(af[m], bfr, acc2[m], 0, 0, 0);
            __builtin_amdgcn_s_setprio(0);
        }
#pragma unroll
        for (int m = 0; m < 4; ++m) {
#pragma unroll
            for (int r = 0; r < 4; ++r) {
                int row = m * 16 + lk * 4 + r;
                int col = n0 + wv * 16 + l15;
                size_t idx = (qrow0 + row) * 1024 + col;
                outp[idx] = acc2[m][r] + b2[col] + xres[idx];
            }
        }
        __syncthreads();
    }
}

extern "C" void kernel_launch(void* const* d_in, const int* in_sizes, int n_in,
                              void* d_out, int out_size, void* d_ws, size_t ws_size,
                              hipStream_t stream) {
    const float* x  = (const float*)d_in[0];
    const float* Wq = (const float*)d_in[1];
    const float* bq = (const float*)d_in[2];
    const float* Wk = (const float*)d_in[3];
    // bk (d_in[4]) contributes only row-constants to scores -> cancels in softmax
    const float* Wv = (const float*)d_in[5];
    const float* bv = (const float*)d_in[6];
    const float* Wo = (const float*)d_in[7];
    const float* bo = (const float*)d_in[8];
    float* out = (float*)d_out;

    char* ws = (char*)d_ws;
    u16* xb  = (u16*)(ws);                    // [16384,1024] bf16
    u16* yb  = (u16*)(ws + 33554432);         // [16384,1024] bf16
    u16* v2t = (u16*)(ws + 67108864);         // [1024,16384] bf16 (v2 transposed)
    u16* WqT = (u16*)(ws + 100663296);        // [1024,1024] bf16
    u16* WkT = (u16*)(ws + 102760448);        // [1024,1024] bf16
    u16* WvT = (u16*)(ws + 104857600);        // [1024,1024] bf16
    u16* Wob = (u16*)(ws + 106954752);        // [1024,1024] bf16
    u16* Hb  = (u16*)(ws + 109051904);        // [1024,1024] bf16 H = Wk^T Wq
    u16* W2b = (u16*)(ws + 111149056);        // [1024,1024] bf16 W2 = Wo Wv
    float* u_  = (float*)(ws + 113246208);    // [1024] fp32
    float* b2_ = (float*)(ws + 113250304);    // [1024] fp32

    cast_f32_bf16<<<8192, 256, 0, stream>>>(x, xb, 16777216);
    wcast<<<1024, 256, 0, stream>>>(Wq, Wk, Wv, Wo, WqT, WkT, WvT, Wob);
    ub2<<<68, 256, 0, stream>>>(Wk, bq, Wo, bv, bo, u_, b2_);
    gemm_small_dual<<<512, 256, 0, stream>>>(WkT, WqT, Hb, Wob, WvT, W2b);
    gemm_yv<<<dim3(16, 128), 256, 0, stream>>>(xb, Hb, W2b, u_, yb, v2t);
    attn_win<<<256, 256, 0, stream>>>(yb, xb, v2t, x, b2_, out);
}

// Round 13
// 196.536 us; speedup vs baseline: 1.2039x; 1.0087x over previous
//
#include <hip/hip_runtime.h>
#include <hip/hip_bf16.h>

// LocalSelfAttention: B=4, S=4096, E=1024, WINDOW=256, SCALE=0.125
// Algebra: scores_ij = (x G + u)_i . x_j (row-consts cancel in softmax),
//   G = Wq^T Wk, u = Wk^T bq.  Since attn rows sum to 1:
//   out = attn @ (x W2^T) + b2 + x,  W2 = Wo Wv, b2 = Wo bv + bo.
// Round 13: gemm_yv gets the T14 1-barrier double-buffer pipeline that paid on
//   attn in r12 (reg-prefetch chunk i+2 || ds-write chunk i+1 || MFMA chunk i).
//   LDS 64KB, 2 blocks/CU. attn unchanged from r12.

typedef unsigned short u16;
typedef __attribute__((ext_vector_type(8))) short short8;   // 8 bf16
typedef __attribute__((ext_vector_type(4))) short short4v;  // 4 bf16 (8B)
typedef __attribute__((ext_vector_type(4))) float f32x4;

__device__ __forceinline__ u16 f2bf(float f) {
    __hip_bfloat16 h = __float2bfloat16(f);
    return __builtin_bit_cast(u16, h);
}

// ---------------- cast fp32 -> bf16, vectorized ----------------
__global__ void cast_f32_bf16(const float* __restrict__ src, u16* __restrict__ dst, int n) {
    int i = (blockIdx.x * 256 + threadIdx.x) * 8;
    if (i >= n) return;
    const float4* s = (const float4*)(src + i);
    float4 a = s[0], b = s[1];
    short8 o;
    o[0] = (short)f2bf(a.x); o[1] = (short)f2bf(a.y); o[2] = (short)f2bf(a.z); o[3] = (short)f2bf(a.w);
    o[4] = (short)f2bf(b.x); o[5] = (short)f2bf(b.y); o[6] = (short)f2bf(b.z); o[7] = (short)f2bf(b.w);
    *(short8*)(dst + i) = o;
}

// ---------------- weight casts: WqT, WkT, WvT (transposed), Wob (straight) ----------------
__global__ void wcast(const float* __restrict__ Wq, const float* __restrict__ Wk,
                      const float* __restrict__ Wv, const float* __restrict__ Wo,
                      u16* __restrict__ WqT, u16* __restrict__ WkT,
                      u16* __restrict__ WvT, u16* __restrict__ Wob)
{
    __shared__ float lt[64][65];
    const int which = blockIdx.x >> 8;
    const int bid = blockIdx.x & 255;
    const int c0 = (bid & 15) * 64, r0 = (bid >> 4) * 64;
    const int t = threadIdx.x;
    const int tr = t >> 3, tc = (t & 7) * 8;
    const float* src = which == 0 ? Wq : which == 1 ? Wk : which == 2 ? Wv : Wo;
    if (which == 3) {
#pragma unroll
        for (int p = 0; p < 2; ++p) {
            int r = p * 32 + tr;
            const float* s = src + (size_t)(r0 + r) * 1024 + c0 + tc;
            float4 a = *(const float4*)s, b = *(const float4*)(s + 4);
            short8 o;
            o[0] = (short)f2bf(a.x); o[1] = (short)f2bf(a.y); o[2] = (short)f2bf(a.z); o[3] = (short)f2bf(a.w);
            o[4] = (short)f2bf(b.x); o[5] = (short)f2bf(b.y); o[6] = (short)f2bf(b.z); o[7] = (short)f2bf(b.w);
            *(short8*)(Wob + (size_t)(r0 + r) * 1024 + c0 + tc) = o;
        }
        return;
    }
    u16* dst = which == 0 ? WqT : which == 1 ? WkT : WvT;
#pragma unroll
    for (int p = 0; p < 2; ++p) {
        int r = p * 32 + tr;
        const float* s = src + (size_t)(r0 + r) * 1024 + c0 + tc;
        float4 a = *(const float4*)s, b = *(const float4*)(s + 4);
        lt[r][tc + 0] = a.x; lt[r][tc + 1] = a.y; lt[r][tc + 2] = a.z; lt[r][tc + 3] = a.w;
        lt[r][tc + 4] = b.x; lt[r][tc + 5] = b.y; lt[r][tc + 6] = b.z; lt[r][tc + 7] = b.w;
    }
    __syncthreads();
#pragma unroll
    for (int p = 0; p < 2; ++p) {
        int r = p * 32 + tr;
        short8 o;
#pragma unroll
        for (int j = 0; j < 8; ++j) o[j] = (short)f2bf(lt[tc + j][r]);
        *(short8*)(dst + (size_t)(c0 + r) * 1024 + r0 + tc) = o;
    }
}

// ---------------- u = Wk^T bq ; b2 = Wo bv + bo (fp32) ----------------
__global__ void ub2(const float* __restrict__ Wk, const float* __restrict__ bq,
                    const float* __restrict__ Wo, const float* __restrict__ bv,
                    const float* __restrict__ bo, float* __restrict__ u, float* __restrict__ b2)
{
    const int t = threadIdx.x, bid = blockIdx.x;
    if (bid < 4) {
        int b = bid * 256 + t;
        float acc = 0.f;
        for (int o = 0; o < 1024; ++o) acc += Wk[(size_t)o * 1024 + b] * bq[o];
        u[b] = acc;
    } else {
        int n = (bid - 4) * 16 + (t >> 4);
        int l = t & 15;
        float acc = 0.f;
        for (int m = l; m < 1024; m += 16) acc += Wo[(size_t)n * 1024 + m] * bv[m];
#pragma unroll
        for (int s = 1; s < 16; s <<= 1) acc += __shfl_xor(acc, s, 64);
        if (l == 0) b2[n] = acc + bo[n];
    }
}

// ---------------- dual small GEMM (1024^3): H = WkT @ WqT^T, W2 = Wob @ WvT^T ----------------
__global__ __launch_bounds__(256, 4) void gemm_small_dual(
    const u16* __restrict__ HA, const u16* __restrict__ HB, u16* __restrict__ HC,
    const u16* __restrict__ WA, const u16* __restrict__ WB, u16* __restrict__ WC)
{
    __shared__ __align__(16) u16 At[64 * 64], Bt[64 * 64];
    const bool sec = blockIdx.x >= 256;
    const u16* A = sec ? WA : HA;
    const u16* B = sec ? WB : HB;
    u16* C = sec ? WC : HC;
    const int bid = blockIdx.x & 255;
    const int m0 = (bid >> 4) * 64, n0 = (bid & 15) * 64;
    const int t = threadIdx.x, lane = t & 63, w = t >> 6;
    const int l15 = lane & 15, lk = lane >> 4;

    f32x4 acc[4];
#pragma unroll
    for (int m = 0; m < 4; ++m) acc[m] = (f32x4){0.f, 0.f, 0.f, 0.f};

    for (int k0 = 0; k0 < 1024; k0 += 64) {
        __syncthreads();
#pragma unroll
        for (int p = 0; p < 2; ++p) {
            int e = p * 2048 + t * 8;
            int row = e >> 6, col = e & 63;
            short8 va = *(const short8*)(A + (size_t)(m0 + row) * 1024 + k0 + col);
            *(short8*)((char*)At + row * 128 + ((col * 2) ^ ((row & 7) << 4))) = va;
            short8 vb = *(const short8*)(B + (size_t)(n0 + row) * 1024 + k0 + col);
            *(short8*)((char*)Bt + row * 128 + ((col * 2) ^ ((row & 7) << 4))) = vb;
        }
        __syncthreads();
#pragma unroll
        for (int ks = 0; ks < 2; ++ks) {
            int bc = ks * 64 + lk * 16;
            int brow = w * 16 + l15;
            short8 bfr = *(const short8*)((char*)Bt + brow * 128 + (bc ^ ((brow & 7) << 4)));
#pragma unroll
            for (int m = 0; m < 4; ++m) {
                int arow = m * 16 + l15;
                short8 af = *(const short8*)((char*)At + arow * 128 + (bc ^ ((arow & 7) << 4)));
                acc[m] = __builtin_amdgcn_mfma_f32_16x16x32_bf16(af, bfr, acc[m], 0, 0, 0);
            }
        }
    }
#pragma unroll
    for (int m = 0; m < 4; ++m)
#pragma unroll
        for (int r = 0; r < 4; ++r) {
            int row = m0 + m * 16 + lk * 4 + r;
            int col = n0 + w * 16 + l15;
            C[(size_t)row * 1024 + col] = f2bf(acc[m][r]);
        }
}

// ---------------- fused dual GEMM: y = x@H + u ; v2t = (x@W2^T)^T ----------------
// 128^2 tile, 256 thr / 4 waves, T14 1-barrier double-buffer. Grid dim3(16,128).
// Ledger: iter i: WRITE(b^1)=chunk i+1 (buffer consumed at iter i-1, freed by
// its end barrier); MFMA reads buf b (written at iter i-1, visible via that
// same barrier's lgkm drain); barrier at end of iter i.
__global__ __launch_bounds__(256, 2) void gemm_yv(
    const u16* __restrict__ A, const u16* __restrict__ BH, const u16* __restrict__ BW,
    const float* __restrict__ ub, u16* __restrict__ Y, u16* __restrict__ V2t)
{
    __shared__ __align__(16) char smbuf[2 * 32768];   // buf b at b*32768: At 16KB + Bt 16KB
    const int t = threadIdx.x;
    const int lane = t & 63;
    const int wid = t >> 6;
    const int wm = wid >> 1, wn = wid & 1;
    const int l15 = lane & 15, lk = lane >> 4;
    const int K = 1024;

    const int bid = blockIdx.y * gridDim.x + blockIdx.x;   // gridDim.x == 16
    const int cpx = 2048 >> 3;
    const int swz = (bid & 7) * cpx + (bid >> 3);
    const int tn = swz & 15;
    const int tm = swz >> 4;
    const int m0 = tm * 128;
    const bool isv = tn >= 8;
    const int n0 = (tn & 7) * 128;
    const u16* B = isv ? BW : BH;

    const int srow = (t * 8) >> 6, scol = (t * 8) & 63;   // + p*32 rows

    f32x4 acc[4][4];
#pragma unroll
    for (int m = 0; m < 4; ++m)
#pragma unroll
        for (int n = 0; n < 4; ++n)
            acc[m][n] = (f32x4){0.f, 0.f, 0.f, 0.f};

    short8 pva[4], pvb[4];
    auto LOAD = [&](int k0) {
#pragma unroll
        for (int p = 0; p < 4; ++p) {
            int row = p * 32 + srow;
            pva[p] = *(const short8*)(A + (size_t)(m0 + row) * K + k0 + scol);
            pvb[p] = *(const short8*)(B + (size_t)(n0 + row) * K + k0 + scol);
        }
    };
    auto WRITE = [&](int b) {
        char* At = smbuf + b * 32768;
        char* Bt = At + 16384;
#pragma unroll
        for (int p = 0; p < 4; ++p) {
            int row = p * 32 + srow;
            *(short8*)(At + row * 128 + ((scol * 2) ^ ((row & 7) << 4))) = pva[p];
            *(short8*)(Bt + row * 128 + ((scol * 2) ^ ((row & 7) << 4))) = pvb[p];
        }
    };

    LOAD(0);
    WRITE(0);
    LOAD(64);
    __syncthreads();

    for (int i = 0; i < 16; ++i) {
        const int b = i & 1;
        if (i + 1 < 16) {
            WRITE(b ^ 1);
            if (i + 2 < 16) LOAD((i + 2) * 64);
        }
        const char* At = smbuf + b * 32768;
        const char* Bt = At + 16384;
#pragma unroll
        for (int ks = 0; ks < 2; ++ks) {
            const int bc = ks * 64 + lk * 16;
            short8 af[4], bfr[4];
#pragma unroll
            for (int m = 0; m < 4; ++m) {
                int row = wm * 64 + m * 16 + l15;
                af[m] = *(const short8*)(At + row * 128 + (bc ^ ((row & 7) << 4)));
            }
#pragma unroll
            for (int n = 0; n < 4; ++n) {
                int row = wn * 64 + n * 16 + l15;
                bfr[n] = *(const short8*)(Bt + row * 128 + (bc ^ ((row & 7) << 4)));
            }
            __builtin_amdgcn_s_setprio(1);
#pragma unroll
            for (int m = 0; m < 4; ++m)
#pragma unroll
                for (int n = 0; n < 4; ++n)
                    acc[m][n] = __builtin_amdgcn_mfma_f32_16x16x32_bf16(af[m], bfr[n], acc[m][n], 0, 0, 0);
            __builtin_amdgcn_s_setprio(0);
        }
        __syncthreads();
    }

    if (!isv) {
#pragma unroll
        for (int m = 0; m < 4; ++m)
#pragma unroll
            for (int n = 0; n < 4; ++n) {
                int col = n0 + wn * 64 + n * 16 + l15;
                float bv = ub[col];
#pragma unroll
                for (int r = 0; r < 4; ++r) {
                    int row = m0 + wm * 64 + m * 16 + lk * 4 + r;
                    Y[(size_t)row * 1024 + col] = f2bf(acc[m][n][r] + bv);
                }
            }
    } else {
#pragma unroll
        for (int m = 0; m < 4; ++m)
#pragma unroll
            for (int n = 0; n < 4; ++n) {
                int col = n0 + wn * 64 + n * 16 + l15;          // e index
                int row0 = m0 + wm * 64 + m * 16 + lk * 4;      // i index base
                short4v pk;
#pragma unroll
                for (int r = 0; r < 4; ++r) pk[r] = (short)f2bf(acc[m][n][r]);
                *(short4v*)(V2t + (size_t)col * 16384 + row0) = pk;
            }
    }
}

// ---------------- windowed causal attention, double-buffered staging (T14, r12) ----------------
__global__ __launch_bounds__(256, 1) void attn_win(
    const u16* __restrict__ y, const u16* __restrict__ xb,
    const u16* __restrict__ vt, const float* __restrict__ xres,
    const float* __restrict__ b2, float* __restrict__ outp)
{
    // [0,81920): staging dbuf, buf b at b*40960: Qt 8KB + Kt 32KB (phase1) / Vl 32KB (phase3)
    // [81920,114688): P bf16 [64][256] swizzled
    // [114688,115712): rmax [64][4] | [115712,116736): rsum [64][4]
    __shared__ __align__(16) char smem[116736];
    u16* P  = (u16*)(smem + 81920);
    float* rmax = (float*)(smem + 114688);
    float* rsum = (float*)(smem + 115712);

    const int t = threadIdx.x;
    const int lane = t & 63, wv = t >> 6;
    const int l15 = lane & 15, lk = lane >> 4;
    const int bid = blockIdx.x;
    const int swz = (bid & 7) * 32 + (bid >> 3);
    const int win = swz >> 2, qc = swz & 3;
    const size_t qrow0 = (size_t)win * 256 + qc * 64;
    const size_t krow0 = (size_t)win * 256;

    f32x4 acc[4][4];
#pragma unroll
    for (int m = 0; m < 4; ++m)
#pragma unroll
        for (int n = 0; n < 4; ++n)
            acc[m][n] = (f32x4){0.f, 0.f, 0.f, 0.f};

    // ---- phase 1: scores = y @ x^T over E=1024, 16 chunks, 2-deep pipeline ----
    short8 pq[2], pk[8];
    auto LOAD_QK = [&](int e0) {
#pragma unroll
        for (int p = 0; p < 2; ++p) {
            int e = p * 2048 + t * 8;
            pq[p] = *(const short8*)(y + (qrow0 + (e >> 6)) * 1024 + e0 + (e & 63));
        }
#pragma unroll
        for (int p = 0; p < 8; ++p) {
            int e = p * 2048 + t * 8;
            pk[p] = *(const short8*)(xb + (krow0 + (e >> 6)) * 1024 + e0 + (e & 63));
        }
    };
    auto WRITE_QK = [&](int b) {
        char* Qt = smem + b * 40960;
        char* Kt = Qt + 8192;
#pragma unroll
        for (int p = 0; p < 2; ++p) {
            int e = p * 2048 + t * 8;
            int row = e >> 6, col = e & 63;
            *(short8*)(Qt + row * 128 + ((col * 2) ^ ((row & 7) << 4))) = pq[p];
        }
#pragma unroll
        for (int p = 0; p < 8; ++p) {
            int e = p * 2048 + t * 8;
            int row = e >> 6, col = e & 63;
            *(short8*)(Kt + row * 128 + ((col * 2) ^ ((row & 7) << 4))) = pk[p];
        }
    };

    LOAD_QK(0);
    WRITE_QK(0);
    LOAD_QK(64);
    __syncthreads();

    for (int i = 0; i < 16; ++i) {
        const int b = i & 1;
        if (i + 1 < 16) {
            WRITE_QK(b ^ 1);
            if (i + 2 < 16) LOAD_QK((i + 2) * 64);
        }
        const char* Qt = smem + b * 40960;
        const char* Kt = Qt + 8192;
#pragma unroll
        for (int ks = 0; ks < 2; ++ks) {
            const int bc = ks * 64 + lk * 16;
            short8 af[4], bfr[4];
#pragma unroll
            for (int m = 0; m < 4; ++m) {
                int row = m * 16 + l15;
                af[m] = *(const short8*)(Qt + row * 128 + (bc ^ ((row & 7) << 4)));
            }
#pragma unroll
            for (int n = 0; n < 4; ++n) {
                int row = wv * 64 + n * 16 + l15;
                bfr[n] = *(const short8*)(Kt + row * 128 + (bc ^ ((row & 7) << 4)));
            }
            __builtin_amdgcn_s_setprio(1);
#pragma unroll
            for (int m = 0; m < 4; ++m)
#pragma unroll
                for (int n = 0; n < 4; ++n)
                    acc[m][n] = __builtin_amdgcn_mfma_f32_16x16x32_bf16(af[m], bfr[n], acc[m][n], 0, 0, 0);
            __builtin_amdgcn_s_setprio(0);
        }
        __syncthreads();
    }

    // ---- phase 2: register softmax ----
#pragma unroll
    for (int m = 0; m < 4; ++m)
#pragma unroll
        for (int n = 0; n < 4; ++n) {
            int col = wv * 64 + n * 16 + l15;
#pragma unroll
            for (int r = 0; r < 4; ++r) {
                int qpos = qc * 64 + m * 16 + lk * 4 + r;
                float v = acc[m][n][r] * 0.125f;
                acc[m][n][r] = (col <= qpos) ? v : -1e30f;
            }
        }
#pragma unroll
    for (int m = 0; m < 4; ++m)
#pragma unroll
        for (int r = 0; r < 4; ++r) {
            float tmx = fmaxf(fmaxf(acc[m][0][r], acc[m][1][r]), fmaxf(acc[m][2][r], acc[m][3][r]));
            tmx = fmaxf(tmx, __shfl_xor(tmx, 1));
            tmx = fmaxf(tmx, __shfl_xor(tmx, 2));
            tmx = fmaxf(tmx, __shfl_xor(tmx, 4));
            tmx = fmaxf(tmx, __shfl_xor(tmx, 8));
            if (l15 == 0) rmax[(m * 16 + lk * 4 + r) * 4 + wv] = tmx;
        }
    __syncthreads();
#pragma unroll
    for (int m = 0; m < 4; ++m)
#pragma unroll
        for (int r = 0; r < 4; ++r) {
            int row = m * 16 + lk * 4 + r;
            float m4 = fmaxf(fmaxf(rmax[row * 4], rmax[row * 4 + 1]),
                             fmaxf(rmax[row * 4 + 2], rmax[row * 4 + 3]));
            float s = 0.f;
#pragma unroll
            for (int n = 0; n < 4; ++n) {
                float e = __expf(acc[m][n][r] - m4);
                acc[m][n][r] = e;
                s += e;
            }
            s += __shfl_xor(s, 1);
            s += __shfl_xor(s, 2);
            s += __shfl_xor(s, 4);
            s += __shfl_xor(s, 8);
            if (l15 == 0) rsum[row * 4 + wv] = s;
        }
    __syncthreads();
#pragma unroll
    for (int m = 0; m < 4; ++m)
#pragma unroll
        for (int r = 0; r < 4; ++r) {
            int row = m * 16 + lk * 4 + r;
            float inv = 1.f / (rsum[row * 4] + rsum[row * 4 + 1] + rsum[row * 4 + 2] + rsum[row * 4 + 3]);
#pragma unroll
            for (int n = 0; n < 4; ++n) {
                int col = wv * 64 + n * 16 + l15;
                *(u16*)((char*)P + row * 512 + ((col * 2) ^ ((row & 7) << 4))) = f2bf(acc[m][n][r] * inv);
            }
        }

    // ---- phase 3: out = attn @ v2 + b2 + x, 16 chunks, 2-deep pipeline ----
    short8 pv[8];
    auto LOAD_V = [&](int n0) {
#pragma unroll
        for (int p = 0; p < 8; ++p) {
            int e = p * 2048 + t * 8;
            pv[p] = *(const short8*)(vt + (size_t)(n0 + (e >> 8)) * 16384 + win * 256 + (e & 255));
        }
    };
    auto WRITE_V = [&](int b) {
        char* Vl = smem + b * 40960;
#pragma unroll
        for (int p = 0; p < 8; ++p) {
            int e = p * 2048 + t * 8;
            int row = e >> 8, col = e & 255;
            *(short8*)(Vl + row * 512 + ((col * 2) ^ ((row & 7) << 4))) = pv[p];
        }
    };

    LOAD_V(0);
    WRITE_V(0);
    LOAD_V(64);
    __syncthreads();

    for (int i = 0; i < 16; ++i) {
        const int b = i & 1;
        const int n0 = i * 64;
        if (i + 1 < 16) {
            WRITE_V(b ^ 1);
            if (i + 2 < 16) LOAD_V((i + 2) * 64);
        }
        const char* Vl = smem + b * 40960;
        f32x4 acc2[4];
#pragma unroll
        for (int m = 0; m < 4; ++m) acc2[m] = (f32x4){0.f, 0.f, 0.f, 0.f};
#pragma unroll
        for (int ks = 0; ks < 8; ++ks) {
            const int bc = ks * 64 + lk * 16;
            short8 af[4];
#pragma unroll
            for (int m = 0; m < 4; ++m) {
                int row = m * 16 + l15;
                af[m] = *(const short8*)((char*)P + row * 512 + (bc ^ ((row & 7) << 4)));
            }
            int vrow = wv * 16 + l15;
            short8 bfr = *(const short8*)(Vl + vrow * 512 + (bc ^ ((vrow & 7) << 4)));
            __builtin_amdgcn_s_setprio(1);
#pragma unroll
            for (int m = 0; m < 4; ++m)
                acc2[m] = __builtin_amdgcn_mfma_f32_16x16x32_bf16(af[m], bfr, acc2[m], 0, 0, 0);
            __builtin_amdgcn_s_setprio(0);
        }
#pragma unroll
        for (int m = 0; m < 4; ++m) {
#pragma unroll
            for (int r = 0; r < 4; ++r) {
                int row = m * 16 + lk * 4 + r;
                int col = n0 + wv * 16 + l15;
                size_t idx = (qrow0 + row) * 1024 + col;
                outp[idx] = acc2[m][r] + b2[col] + xres[idx];
            }
        }
        __syncthreads();
    }
}

extern "C" void kernel_launch(void* const* d_in, const int* in_sizes, int n_in,
                              void* d_out, int out_size, void* d_ws, size_t ws_size,
                              hipStream_t stream) {
    const float* x  = (const float*)d_in[0];
    const float* Wq = (const float*)d_in[1];
    const float* bq = (const float*)d_in[2];
    const float* Wk = (const float*)d_in[3];
    // bk (d_in[4]) contributes only row-constants to scores -> cancels in softmax
    const float* Wv = (const float*)d_in[5];
    const float* bv = (const float*)d_in[6];
    const float* Wo = (const float*)d_in[7];
    const float* bo = (const float*)d_in[8];
    float* out = (float*)d_out;

    char* ws = (char*)d_ws;
    u16* xb  = (u16*)(ws);                    // [16384,1024] bf16
    u16* yb  = (u16*)(ws + 33554432);         // [16384,1024] bf16
    u16* v2t = (u16*)(ws + 67108864);         // [1024,16384] bf16 (v2 transposed)
    u16* WqT = (u16*)(ws + 100663296);        // [1024,1024] bf16
    u16* WkT = (u16*)(ws + 102760448);        // [1024,1024] bf16
    u16* WvT = (u16*)(ws + 104857600);        // [1024,1024] bf16
    u16* Wob = (u16*)(ws + 106954752);        // [1024,1024] bf16
    u16* Hb  = (u16*)(ws + 109051904);        // [1024,1024] bf16 H = Wk^T Wq
    u16* W2b = (u16*)(ws + 111149056);        // [1024,1024] bf16 W2 = Wo Wv
    float* u_  = (float*)(ws + 113246208);    // [1024] fp32
    float* b2_ = (float*)(ws + 113250304);    // [1024] fp32

    cast_f32_bf16<<<8192, 256, 0, stream>>>(x, xb, 16777216);
    wcast<<<1024, 256, 0, stream>>>(Wq, Wk, Wv, Wo, WqT, WkT, WvT, Wob);
    ub2<<<68, 256, 0, stream>>>(Wk, bq, Wo, bv, bo, u_, b2_);
    gemm_small_dual<<<512, 256, 0, stream>>>(WkT, WqT, Hb, Wob, WvT, W2b);
    gemm_yv<<<dim3(16, 128), 256, 0, stream>>>(xb, Hb, W2b, u_, yb, v2t);
    attn_win<<<256, 256, 0, stream>>>(yb, xb, v2t, x, b2_, out);
}